// Round 7
// baseline (130.040 us; speedup 1.0000x reference)
//
#include <hip/hip_runtime.h>
#include <math.h>

#define BB 4
#define NN 512
#define DD 256
#define HH 8
#define BND (BB*NN*DD)

typedef _Float16 h2 __attribute__((ext_vector_type(2)));

static __device__ __forceinline__ h2 u2h(unsigned u) { return __builtin_bit_cast(h2, u); }
static __device__ __forceinline__ float u2f(unsigned u) { return __builtin_bit_cast(float, u); }
// RNE pack (v_cvt_f16_f32 x2 + v_pack_b32_f16) — NOT cvt_pkrtz (RTZ doubles RMS error)
static __device__ __forceinline__ h2 pk2(float a, float b) {
    h2 r; r[0] = (_Float16)a; r[1] = (_Float16)b; return r;
}
static __device__ __forceinline__ unsigned pk2u(float a, float b) {
    return __builtin_bit_cast(unsigned, pk2(a, b));
}
static __device__ __forceinline__ float dot2(h2 a, h2 b, float c) {
    return __builtin_amdgcn_fdot2(a, b, c, false);
}

constexpr int RB = 8;   // rows per block in the row-GEMM kernels

// ---------------- pack bias-MLP weights into per-c-pair records ----------------
// record cp (c0=2cp,c1=2cp+1), 16 dwords:
// [0]=(w1x,w1y)c0 f16x2  [1]=(w1d,w1t)c0  [2],[3]= same c1
// [4]=b1[c0] f32  [5]=b1[c1] f32  [6..13]=(W2[c0][h],W2[c1][h]) f16x2  [14,15]=0
__global__ __launch_bounds__(128) void pack_w2(
    const float* __restrict__ W1, const float* __restrict__ b1,
    const float* __restrict__ W2, unsigned* __restrict__ pw2)
{
    const int cp = threadIdx.x;       // 0..127
    const int c0 = 2*cp, c1 = c0 + 1;
    unsigned r[16];
    r[0] = pk2u(W1[c0],      W1[DD + c0]);
    r[1] = pk2u(W1[2*DD+c0], W1[3*DD + c0]);
    r[2] = pk2u(W1[c1],      W1[DD + c1]);
    r[3] = pk2u(W1[2*DD+c1], W1[3*DD + c1]);
    r[4] = __builtin_bit_cast(unsigned, b1[c0]);
    r[5] = __builtin_bit_cast(unsigned, b1[c1]);
    #pragma unroll
    for (int h = 0; h < HH; ++h)
        r[6+h] = pk2u(W2[c0*HH + h], W2[c1*HH + h]);
    r[14] = r[15] = 0u;
    #pragma unroll
    for (int u = 0; u < 16; ++u) pw2[cp*16 + u] = r[u];
}

// ---------------- QKV projection ----------------
// emits q16 (f16), k16 (f16, pre-scaled by 1/sqrt(32)), v16 packed [j/2][c] pairs
__global__ __launch_bounds__(256) void qkv_proj(
    const float* __restrict__ hg, const int* __restrict__ mask,
    const float* __restrict__ Wq, const float* __restrict__ Wk, const float* __restrict__ Wv,
    _Float16* __restrict__ q16, _Float16* __restrict__ k16, _Float16* __restrict__ v16h)
{
    __shared__ float hsT[DD][RB];
    const int t = threadIdx.x;
    const int r0 = blockIdx.x * RB;
    #pragma unroll
    for (int rr = 0; rr < RB; ++rr) {
        float x = hg[(size_t)(r0 + rr) * DD + t];
        if (mask[r0 + rr] == 0) x = 0.f;
        hsT[t][rr] = x;
    }
    __syncthreads();
    float aq[RB], ak[RB], av[RB];
    #pragma unroll
    for (int rr = 0; rr < RB; ++rr) { aq[rr] = 0.f; ak[rr] = 0.f; av[rr] = 0.f; }
    for (int d = 0; d < DD; ++d) {
        const float wq = Wq[d*DD + t];
        const float wk = Wk[d*DD + t];
        const float wv = Wv[d*DD + t];
        const float4 h0 = *(const float4*)&hsT[d][0];
        const float4 h1 = *(const float4*)&hsT[d][4];
        const float hv[8] = {h0.x,h0.y,h0.z,h0.w,h1.x,h1.y,h1.z,h1.w};
        #pragma unroll
        for (int rr = 0; rr < RB; ++rr) {
            aq[rr] = fmaf(hv[rr], wq, aq[rr]);
            ak[rr] = fmaf(hv[rr], wk, ak[rr]);
            av[rr] = fmaf(hv[rr], wv, av[rr]);
        }
    }
    const float qscale = 0.17677669529663687f; // 1/sqrt(32)
    #pragma unroll
    for (int rr = 0; rr < RB; ++rr) {
        const int r = r0 + rr;
        q16[(size_t)r*DD + t] = (_Float16)aq[rr];
        k16[(size_t)r*DD + t] = (_Float16)(ak[rr] * qscale);
        // packed-pair layout: dword (r>>1)*DD + t holds (v[2m][c], v[2m+1][c])
        v16h[((size_t)(r >> 1)*DD + t)*2 + (r & 1)] = (_Float16)av[rr];
    }
}

// ---------------- fused bias-MLP + QK^T + softmax + PV ----------------
// block = (b, 2 query rows), 256 threads; thread t owns adjacent key cols 2t, 2t+1.
// 1024 blocks -> 4 blocks/CU -> 16 waves/CU (grid was the occupancy cap at 512).
__global__ __launch_bounds__(256, 4) void fused_attn(
    const unsigned* __restrict__ q16u, const unsigned* __restrict__ k16u,
    const unsigned* __restrict__ v16p,
    const float* __restrict__ p, const int* __restrict__ side, const int* __restrict__ mask,
    const unsigned* __restrict__ pw2, const float* __restrict__ b2,
    float* __restrict__ ao)
{
    __shared__ unsigned Lgh[16][260];    // 16.6 KB packed f16 pairs: logits -> exp
    __shared__ float red[16][16];
    __shared__ float mx[16];
    __shared__ float rs[16];

    const int t  = threadIdx.x;
    const int b  = blockIdx.x / (NN/2);
    const int i0 = (blockIdx.x % (NN/2)) * 2;

    float pix[2], piy[2]; int si[2];
    #pragma unroll
    for (int ii = 0; ii < 2; ++ii) {
        pix[ii] = p[(size_t)(b*NN + i0 + ii)*2 + 0];
        piy[ii] = p[(size_t)(b*NN + i0 + ii)*2 + 1];
        si[ii]  = side[b*NN + i0 + ii];
    }

    const int j0 = 2*t, j1 = 2*t + 1;
    const float pjx0 = p[(size_t)(b*NN + j0)*2 + 0];
    const float pjy0 = p[(size_t)(b*NN + j0)*2 + 1];
    const float pjx1 = p[(size_t)(b*NN + j1)*2 + 0];
    const float pjy1 = p[(size_t)(b*NN + j1)*2 + 1];
    const int   sj0  = side[b*NN + j0];
    const int   sj1  = side[b*NN + j1];
    // -3e4 (f16-representable) instead of -1e9: same softmax result
    const float km0  = (mask[b*NN + j0] != 0) ? 0.f : -3.0e4f;
    const float km1  = (mask[b*NN + j1] != 0) ? 0.f : -3.0e4f;

    // packed pairwise features: (dx,dy) and (dist,team) as f16x2 (RNE)
    h2 fxy[2][2], fdt[2][2];
    #pragma unroll
    for (int js = 0; js < 2; ++js) {
        const float px = js ? pjx1 : pjx0;
        const float py = js ? pjy1 : pjy0;
        const int   ss = js ? sj1  : sj0;
        #pragma unroll
        for (int ii = 0; ii < 2; ++ii) {
            const float dx = pix[ii] - px;
            const float dy = piy[ii] - py;
            const float di = fmaxf(sqrtf(dx*dx + dy*dy), 1e-6f);
            const float tm = (si[ii] == ss) ? 1.f : 0.f;
            fxy[js][ii] = pk2(dx, dy);
            fdt[js][ii] = pk2(di, tm);
        }
    }

    float b2r[HH];
    #pragma unroll
    for (int hh = 0; hh < HH; ++hh) b2r[hh] = b2[hh];

    float acc[2][2][HH];
    #pragma unroll
    for (int js = 0; js < 2; ++js) {
        const float kmv = js ? km1 : km0;
        #pragma unroll
        for (int ii = 0; ii < 2; ++ii)
            #pragma unroll
            for (int hh = 0; hh < HH; ++hh)
                acc[js][ii][hh] = b2r[hh] + kmv;
    }

    const unsigned* kr0 = k16u + (size_t)(b*NN + j0)*(DD/2);
    const unsigned* kr1 = kr0 + (DD/2);
    const unsigned* qu  = q16u + (size_t)(b*NN + i0)*(DD/2);

    // c-pair loop: 128 pairs; head hh covers cp in [hh*16, hh*16+16)
    #pragma unroll
    for (int hh = 0; hh < HH; ++hh) {
        for (int g = 0; g < 4; ++g) {
            const int cp0 = hh*16 + g*4;
            const uint4 ka = *(const uint4*)(kr0 + cp0);
            const uint4 kb = *(const uint4*)(kr1 + cp0);
            #pragma unroll
            for (int u = 0; u < 4; ++u) {
                const int cp = cp0 + u;
                const unsigned* rec = pw2 + cp*16;
                const h2 wxy0 = u2h(rec[0]);
                const h2 wdt0 = u2h(rec[1]);
                const h2 wxy1 = u2h(rec[2]);
                const h2 wdt1 = u2h(rec[3]);
                const float b10 = u2f(rec[4]);
                const float b11 = u2f(rec[5]);
                h2 w2p[HH];
                #pragma unroll
                for (int h = 0; h < HH; ++h) w2p[h] = u2h(rec[6+h]);
                h2 qp[2];
                #pragma unroll
                for (int ii = 0; ii < 2; ++ii) qp[ii] = u2h(qu[ii*(DD/2) + cp]);
                #pragma unroll
                for (int js = 0; js < 2; ++js) {
                    const h2 kp = u2h(js ? (&kb.x)[u] : (&ka.x)[u]);
                    #pragma unroll
                    for (int ii = 0; ii < 2; ++ii) {
                        const float a0 = dot2(fxy[js][ii], wxy0, dot2(fdt[js][ii], wdt0, b10));
                        const float a1 = dot2(fxy[js][ii], wxy1, dot2(fdt[js][ii], wdt1, b11));
                        // pack then packed-relu (rounding commutes with relu)
                        h2 ap = pk2(a0, a1);
                        ap = __builtin_elementwise_max(ap, h2{(_Float16)0.f, (_Float16)0.f});
                        float* A = acc[js][ii];
                        #pragma unroll
                        for (int h = 0; h < HH; ++h) A[h] = dot2(ap, w2p[h], A[h]);
                        A[hh] = dot2(qp[ii], kp, A[hh]);   // QK^T (k pre-scaled)
                    }
                }
            }
        }
    }

    // write packed logits to LDS (row = ii*8+hh, col = t) — conflict-free
    #pragma unroll
    for (int ii = 0; ii < 2; ++ii)
        #pragma unroll
        for (int hh = 0; hh < HH; ++hh)
            Lgh[ii*8 + hh][t] = pk2u(acc[0][ii][hh], acc[1][ii][hh]);
    __syncthreads();

    // ---- softmax over j for each of 16 rows (ii,hh); 16 threads per row ----
    const int combo = t >> 4;        // 0..15 = row
    const int sub   = t & 15;
    {
        h2 pm = u2h(0xFC00FC00u);  // (-inf, -inf)
        for (int jp = sub; jp < NN/2; jp += 16)
            pm = __builtin_elementwise_max(pm, u2h(Lgh[combo][jp]));
        red[combo][sub] = fmaxf((float)pm[0], (float)pm[1]);
    }
    __syncthreads();
    if (t < 16) {
        float mm = red[t][0];
        #pragma unroll
        for (int s = 1; s < 16; ++s) mm = fmaxf(mm, red[t][s]);
        mx[t] = mm;
    }
    __syncthreads();
    {
        const float M = mx[combo];
        float s = 0.f;
        for (int jp = sub; jp < NN/2; jp += 16) {
            const h2 l = u2h(Lgh[combo][jp]);
            const float e0 = __expf((float)l[0] - M);
            const float e1 = __expf((float)l[1] - M);
            s += e0 + e1;
            Lgh[combo][jp] = pk2u(e0, e1);
        }
        red[combo][sub] = s;
    }
    __syncthreads();
    if (t < 16) {
        float s = 0.f;
        #pragma unroll
        for (int ss = 0; ss < 16; ++ss) s += red[t][ss];
        rs[t] = 1.f / s;
    }
    __syncthreads();

    // ---- PV: thread t owns output column c = t; dot2 over packed j-pairs ----
    {
        const int c = t;
        const int hh = c >> 5;
        const unsigned* vb = v16p + (size_t)b*(NN/2)*DD + c;
        float o[2] = {0.f, 0.f};
        for (int jp = 0; jp < NN/2; ++jp) {
            const h2 vp = u2h(vb[(size_t)jp*DD]);
            #pragma unroll
            for (int ii = 0; ii < 2; ++ii)
                o[ii] = dot2(u2h(Lgh[ii*8 + hh][jp]), vp, o[ii]);
        }
        #pragma unroll
        for (int ii = 0; ii < 2; ++ii)
            ao[(size_t)(b*NN + i0 + ii)*DD + c] = o[ii] * rs[ii*8 + hh];
    }
}

// ---------------- output projection: out = ao @ Wo ----------------
__global__ __launch_bounds__(256) void oproj(
    const float* __restrict__ X, const float* __restrict__ W, float* __restrict__ Y)
{
    __shared__ float xsT[DD][RB];
    const int t = threadIdx.x;
    const int r0 = blockIdx.x * RB;
    #pragma unroll
    for (int rr = 0; rr < RB; ++rr)
        xsT[t][rr] = X[(size_t)(r0 + rr)*DD + t];
    __syncthreads();
    float a[RB];
    #pragma unroll
    for (int rr = 0; rr < RB; ++rr) a[rr] = 0.f;
    for (int d = 0; d < DD; ++d) {
        const float w = W[d*DD + t];
        const float4 h0 = *(const float4*)&xsT[d][0];
        const float4 h1 = *(const float4*)&xsT[d][4];
        const float hv[8] = {h0.x,h0.y,h0.z,h0.w,h1.x,h1.y,h1.z,h1.w};
        #pragma unroll
        for (int rr = 0; rr < RB; ++rr)
            a[rr] = fmaf(hv[rr], w, a[rr]);
    }
    #pragma unroll
    for (int rr = 0; rr < RB; ++rr)
        Y[(size_t)(r0 + rr)*DD + t] = a[rr];
}

extern "C" void kernel_launch(void* const* d_in, const int* in_sizes, int n_in,
                              void* d_out, int out_size, void* d_ws, size_t ws_size,
                              hipStream_t stream) {
    const float* hg   = (const float*)d_in[0];
    const float* p    = (const float*)d_in[1];
    const int*   side = (const int*)d_in[2];
    const int*   mask = (const int*)d_in[3];
    const float* Wq   = (const float*)d_in[4];
    const float* Wk   = (const float*)d_in[5];
    const float* Wv   = (const float*)d_in[6];
    const float* Wo   = (const float*)d_in[7];
    const float* W1   = (const float*)d_in[8];
    const float* b1   = (const float*)d_in[9];
    const float* W2   = (const float*)d_in[10];
    const float* b2   = (const float*)d_in[11];

    float* ws = (float*)d_ws;
    float* ao = ws;                                   // BND f32
    _Float16* q16 = (_Float16*)(ws + BND);            // BND f16
    _Float16* k16 = q16 + BND;                        // BND f16
    _Float16* v16 = k16 + BND;                        // BND f16 (packed pairs)
    unsigned* pw2 = (unsigned*)(v16 + BND);           // 128*16 u32

    pack_w2<<<1, 128, 0, stream>>>(W1, b1, W2, pw2);
    qkv_proj<<<(BB*NN)/RB, 256, 0, stream>>>(hg, mask, Wq, Wk, Wv, q16, k16, v16);
    fused_attn<<<BB*(NN/2), 256, 0, stream>>>((const unsigned*)q16, (const unsigned*)k16,
                                              (const unsigned*)v16, p, side, mask, pw2, b2, ao);
    oproj<<<(BB*NN)/RB, 256, 0, stream>>>(ao, Wo, (float*)d_out);
}